// Round 4
// baseline (1413.493 us; speedup 1.0000x reference)
//
#include <hip/hip_runtime.h>

// Problem: VOCAB=32000, H=1024, L=256, B=64.  Only batch row 0 matters
// (reference broadcasts hs[:, :1, :]) -> single-sequence GRU, latency-bound.
#define SENT 0xAAAAAAAAu

__device__ __forceinline__ float sigf(float x) { return 1.0f / (1.0f + __expf(-x)); }
__device__ __forceinline__ float tanh_fast(float x) {
  float e = __expf(2.0f * x);
  return 1.0f - 2.0f / (e + 1.0f);
}

// ---------- K1: gi[t][j] = emb[x[t][0]] . w_ih[j] + b_ih[j] (+ b_hh[j] for j<2048) ----------
__global__ __launch_bounds__(256) void k1_gi(const int* __restrict__ x,
                                             const float* __restrict__ emb,
                                             const float* __restrict__ w_ih,
                                             const float* __restrict__ b_ih,
                                             const float* __restrict__ b_hh,
                                             float* __restrict__ gi)
{
  const int j0 = blockIdx.x * 4;
  const int t  = threadIdx.x;
  const int idx = x[t * 64];                       // x[t][0]
  const float* er = emb + (size_t)idx * 1024;

  float acc[4];
#pragma unroll
  for (int j = 0; j < 4; ++j) {
    const int jj = j0 + j;
    acc[j] = b_ih[jj] + (jj < 2048 ? b_hh[jj] : 0.0f);  // fold b_hh for r,z gates
  }

  for (int kc = 0; kc < 1024; kc += 16) {
    const float4 e0 = *(const float4*)(er + kc);
    const float4 e1 = *(const float4*)(er + kc + 4);
    const float4 e2 = *(const float4*)(er + kc + 8);
    const float4 e3 = *(const float4*)(er + kc + 12);
    const float e[16] = {e0.x, e0.y, e0.z, e0.w, e1.x, e1.y, e1.z, e1.w,
                         e2.x, e2.y, e2.z, e2.w, e3.x, e3.y, e3.z, e3.w};
#pragma unroll
    for (int j = 0; j < 4; ++j) {
      const float* w = w_ih + (size_t)(j0 + j) * 1024 + kc;  // wave-uniform -> s_load
#pragma unroll
      for (int i = 0; i < 16; ++i) acc[j] = fmaf(e[i], w[i], acc[j]);
    }
  }
  *(float4*)(gi + (size_t)t * 3072 + j0) = make_float4(acc[0], acc[1], acc[2], acc[3]);
}

// ---------- K2 mega: recurrence + frontier-chasing feat broadcast + final sigmoid ----------
// Blocks 0..255: recurrence. Block g, wave wv owns h element hj = 4g+wv; its three w_hh
//   rows live in 48 fp32 VGPRs (volatile loads -> compiler CANNOT sink them into the loop;
//   R3's VGPR_Count=40 proved the pin failed and every step re-read L2).
//   Per step: each wave polls its quarter of row t-1 (2 coalesced u64 agent-atomic loads
//   per lane, both in flight), writes it into double-buffered hlds, ONE barrier, dot from
//   LDS (k = j*256 + lane*4 + c, m97-style b128 pattern), 6-stage shuffle reduce x3,
//   gate math, one 4B agent-atomic store. Double buffer makes barrier2 unnecessary:
//   a wave reaches iter t+1 only after all waves passed barrier(t), which post-dates
//   every read of the buffer it overwrites.
// Blocks 256..319: broadcast block b = g-256 copies each hseq row (sentinel-polled) to
//   feat[b] as coalesced u64 stores -> the 64 MB write overlaps the recurrence.
// Block 256 wave 0: after copying, polls done-counter (release-fenced by producers),
//   then writes the 64 sigmoid outputs.
__global__ __launch_bounds__(256, 1) void k2_mega(const float* __restrict__ w_hh,
                                                  const float* __restrict__ b_hh,
                                                  const float* __restrict__ gi,
                                                  const float* __restrict__ w_out,
                                                  const float* __restrict__ b_out,
                                                  unsigned int* __restrict__ hseq,
                                                  float* __restrict__ out,
                                                  float* __restrict__ acc,
                                                  unsigned int* __restrict__ cnt)
{
  const int tid  = threadIdx.x;
  const int wv   = tid >> 6;
  const int lane = tid & 63;
  const unsigned long long* hs64 = (const unsigned long long*)hseq;

  if (blockIdx.x < 256) {
    // ================= recurrence =================
    __shared__ float hlds[2][1024];
    const int hj = __builtin_amdgcn_readfirstlane(blockIdx.x * 4 + wv);

    // weights: w[gate*4+j] = row[j*256 + lane*4 .. +3]; volatile => stays in VGPRs
    float4 w[12];
    {
      const volatile float* r0 = w_hh + (size_t)hj * 1024;
      const volatile float* r1 = w_hh + (size_t)(1024 + hj) * 1024;
      const volatile float* r2 = w_hh + (size_t)(2048 + hj) * 1024;
#pragma unroll
      for (int j = 0; j < 4; ++j) {
        const int o = j * 256 + lane * 4;
        w[j]     = make_float4(r0[o], r0[o + 1], r0[o + 2], r0[o + 3]);
        w[4 + j] = make_float4(r1[o], r1[o + 1], r1[o + 2], r1[o + 3]);
        w[8 + j] = make_float4(r2[o], r2[o + 1], r2[o + 2], r2[o + 3]);
      }
    }
    const float bhh_n = b_hh[2048 + hj];
    float hp = 0.0f, wout_acc = 0.0f;

#pragma unroll 1
    for (int t = 0; t < 256; ++t) {
      // wave-uniform scalar prefetches (overlap the poll round-trip)
      const float gi_r = gi[(size_t)t * 3072 + hj];
      const float gi_z = gi[(size_t)t * 3072 + 1024 + hj];
      const float gi_n = gi[(size_t)t * 3072 + 2048 + hj];
      const float wo   = w_out[(size_t)t * 1024 + hj];

      float ar = 0.f, az = 0.f, an = 0.f;

      if (t > 0) {
        // poll own quarter of row t-1: two u64 agent-atomic loads in flight per round
        const unsigned long long* p = hs64 + (size_t)(t - 1) * 512 + wv * 128 + lane;
        unsigned long long a, b;
        for (;;) {
          a = __hip_atomic_load(p,      __ATOMIC_RELAXED, __HIP_MEMORY_SCOPE_AGENT);
          b = __hip_atomic_load(p + 64, __ATOMIC_RELAXED, __HIP_MEMORY_SCOPE_AGENT);
          const bool ok = (((unsigned int)a) != SENT) & (((unsigned int)(a >> 32)) != SENT) &
                          (((unsigned int)b) != SENT) & (((unsigned int)(b >> 32)) != SENT);
          if (__all(ok)) break;
        }
        const int buf = (t - 1) & 1;
        *(unsigned long long*)&hlds[buf][wv * 256 + lane * 2]       = a;
        *(unsigned long long*)&hlds[buf][wv * 256 + 128 + lane * 2] = b;
        __syncthreads();                       // hlds[buf] fully valid

        // dot: lane owns k = j*256 + lane*4 + c
#pragma unroll
        for (int j = 0; j < 4; ++j) {
          const float4 h4 = *(const float4*)&hlds[buf][j * 256 + lane * 4];
          const float4 wr = w[j], wz = w[4 + j], wn = w[8 + j];
          ar = fmaf(h4.x, wr.x, ar); ar = fmaf(h4.y, wr.y, ar);
          ar = fmaf(h4.z, wr.z, ar); ar = fmaf(h4.w, wr.w, ar);
          az = fmaf(h4.x, wz.x, az); az = fmaf(h4.y, wz.y, az);
          az = fmaf(h4.z, wz.z, az); az = fmaf(h4.w, wz.w, az);
          an = fmaf(h4.x, wn.x, an); an = fmaf(h4.y, wn.y, an);
          an = fmaf(h4.z, wn.z, an); an = fmaf(h4.w, wn.w, an);
        }
#pragma unroll
        for (int m = 1; m < 64; m <<= 1) {
          ar += __shfl_xor(ar, m, 64);
          az += __shfl_xor(az, m, 64);
          an += __shfl_xor(an, m, 64);
        }
      }

      const float r  = sigf(ar + gi_r);        // b_ih+b_hh folded into gi_r/gi_z
      const float z  = sigf(az + gi_z);
      const float n  = tanh_fast(gi_n + r * (an + bhh_n));
      const float h2 = (1.0f - z) * n + z * hp;

      unsigned int bits = __float_as_uint(h2);
      if (bits == SENT) bits ^= 1u;            // never store the sentinel
      if (lane == 0) {
        __hip_atomic_store(hseq + (size_t)t * 1024 + hj, bits, __ATOMIC_RELAXED,
                           __HIP_MEMORY_SCOPE_AGENT);
        wout_acc = fmaf(__uint_as_float(bits), wo, wout_acc);
      }
      hp = __uint_as_float(bits);
    }

    if (lane == 0) {
      atomicAdd(acc, wout_acc);                               // device-scope
      __builtin_amdgcn_fence(__ATOMIC_RELEASE, "agent");      // acc visible before cnt
      __hip_atomic_fetch_add(cnt, 1u, __ATOMIC_RELAXED, __HIP_MEMORY_SCOPE_AGENT);
    }
  } else {
    // ================= frontier-chasing broadcast =================
    const int b = blockIdx.x - 256;
    unsigned long long* dst = (unsigned long long*)(out + (size_t)b * 262144);

#pragma unroll 1
    for (int t = 0; t < 256; ++t) {
      const unsigned long long* p = hs64 + (size_t)t * 512 + wv * 128 + lane;
      unsigned long long a, bb;
      for (;;) {
        a  = __hip_atomic_load(p,      __ATOMIC_RELAXED, __HIP_MEMORY_SCOPE_AGENT);
        bb = __hip_atomic_load(p + 64, __ATOMIC_RELAXED, __HIP_MEMORY_SCOPE_AGENT);
        const bool ok = (((unsigned int)a) != SENT) & (((unsigned int)(a >> 32)) != SENT) &
                        (((unsigned int)bb) != SENT) & (((unsigned int)(bb >> 32)) != SENT);
        if (__all(ok)) break;
      }
      dst[(size_t)t * 512 + wv * 128 + lane]      = a;
      dst[(size_t)t * 512 + wv * 128 + 64 + lane] = bb;
    }

    if (blockIdx.x == 256 && wv == 0) {
      if (lane == 0) {
        while (__hip_atomic_load(cnt, __ATOMIC_RELAXED, __HIP_MEMORY_SCOPE_AGENT) != 1024u) {}
      }
      // wave reconverges; all acc adds committed (producers release-fenced before cnt)
      const float a = __hip_atomic_load(acc, __ATOMIC_RELAXED, __HIP_MEMORY_SCOPE_AGENT);
      const float s = sigf(a + b_out[0]);
      out[(size_t)16777216 + lane] = s;
    }
  }
}

// ---------- launch ----------
extern "C" void kernel_launch(void* const* d_in, const int* in_sizes, int n_in,
                              void* d_out, int out_size, void* d_ws, size_t ws_size,
                              hipStream_t stream) {
  const int*   x     = (const int*)d_in[0];
  const float* emb   = (const float*)d_in[1];
  const float* w_ih  = (const float*)d_in[2];
  const float* w_hh  = (const float*)d_in[3];
  const float* b_ih  = (const float*)d_in[4];
  const float* b_hh  = (const float*)d_in[5];
  const float* w_out = (const float*)d_in[6];
  const float* b_out = (const float*)d_in[7];
  float* out = (float*)d_out;

  char* ws = (char*)d_ws;
  float*        gi   = (float*)ws;                       // 3,145,728 B
  unsigned int* hseq = (unsigned int*)(ws + 3145728);    // 1,048,576 B
  float*        acc  = (float*)(ws + 4194304);           // 4 B
  unsigned int* cnt  = (unsigned int*)(ws + 4194308);    // 4 B

  hipMemsetAsync(hseq, 0xAA, (size_t)256 * 1024 * 4, stream);  // sentinel init
  hipMemsetAsync(acc, 0, 8, stream);                           // acc + cnt

  hipLaunchKernelGGL(k1_gi,   dim3(768), dim3(256), 0, stream, x, emb, w_ih, b_ih, b_hh, gi);
  hipLaunchKernelGGL(k2_mega, dim3(320), dim3(256), 0, stream,
                     w_hh, b_hh, gi, w_out, b_out, hseq, out, acc, cnt);
}